// Round 6
// baseline (96.434 us; speedup 1.0000x reference)
//
#include <hip/hip_runtime.h>
#include <hip/hip_bf16.h>

#define H     4
#define HID   256
#define CDIM  512
#define NCH   32              // d-chunks per head in fused prep
#define DPER  (HID / NCH)     // 8 rows per chunk
#define NB    2048            // blocks in score pass

typedef float f32x4 __attribute__((ext_vector_type(4)));

// ws layout (float offsets)
#define WS_P1   0                        // H*NCH*CDIM  w1 partials
#define WS_P2   (WS_P1 + H * NCH * CDIM) // H*NCH*CDIM  w2 partials
#define WS_W2   (WS_P2 + H * NCH * CDIM) // H*CDIM
#define WS_PRE  (WS_W2 + H * CDIM)       // H
#define WS_BMS  (WS_PRE + H)             // H*NB*2 (max,sum interleaved)
#define WS_CNT  (WS_BMS + H * NB * 2)    // H counters, 16 floats apart (64B)

// Fused prep: 128 blocks. Each block computes its (head,chunk) partials; the
// last-arriving block per head (mod-32 counter -> no reset needed, works from
// any poison value) reduces that head's partials to w2[h,*] and pre[h].
// Final reduce is a fixed-order sum -> bit-deterministic regardless of winner.
__global__ void __launch_bounds__(256) prep_kernel(
    const float* __restrict__ pe, const float* __restrict__ Ws,
    const float* __restrict__ bs, const float* __restrict__ as_,
    float* __restrict__ ws)
{
    const int h = blockIdx.x >> 5, chunk = blockIdx.x & (NCH - 1);
    const int t = threadIdx.x;
    const float* W  = Ws + ((size_t)h * HID + chunk * DPER) * CDIM;
    const float* a1 = as_ + (size_t)h * 2 * HID + chunk * DPER;
    const float* a2 = a1 + HID;
    const int c0 = t, c1 = t + 256;
    float w1a = 0.f, w1b = 0.f, w2a = 0.f, w2b = 0.f;
#pragma unroll
    for (int d = 0; d < DPER; ++d) {
        float x0 = W[d * CDIM + c0], x1 = W[d * CDIM + c1];
        float v1 = a1[d], v2 = a2[d];
        w1a = fmaf(v1, x0, w1a); w2a = fmaf(v2, x0, w2a);
        w1b = fmaf(v1, x1, w1b); w2b = fmaf(v2, x1, w2b);
    }
    size_t base = (size_t)(h * NCH + chunk) * CDIM;
    ws[WS_P1 + base + c0] = w1a; ws[WS_P1 + base + c1] = w1b;
    ws[WS_P2 + base + c0] = w2a; ws[WS_P2 + base + c1] = w2b;

    __threadfence();          // release this block's partials (device scope)
    __syncthreads();          // all threads' stores fenced before the atomic

    __shared__ int won;
    if (t == 0) {
        unsigned old = atomicAdd((unsigned*)&ws[WS_CNT + h * 16], 1u);
        won = ((old & (NCH - 1)) == (NCH - 1)) ? 1 : 0;
    }
    __syncthreads();
    if (!won) return;

    __threadfence();          // acquire: all 32 chunks' partials visible

    // final reduce for head h (old prepB body)
    float s1a = 0.f, s1b = 0.f, s2a = 0.f, s2b = 0.f;
#pragma unroll
    for (int k = 0; k < NCH; ++k) {
        size_t b2 = (size_t)(h * NCH + k) * CDIM;
        s1a += ws[WS_P1 + b2 + c0]; s1b += ws[WS_P1 + b2 + c1];
        s2a += ws[WS_P2 + b2 + c0]; s2b += ws[WS_P2 + b2 + c1];
    }
    ws[WS_W2 + h * CDIM + c0] = s2a;
    ws[WS_W2 + h * CDIM + c1] = s2b;
    const float* fa1 = as_ + (size_t)h * 2 * HID;
    const float* fa2 = fa1 + HID;
    float contrib = s1a * pe[c0] + s1b * pe[c1];
    contrib += bs[h * HID + t] * (fa1[t] + fa2[t]);
    __shared__ float red[256];
    red[t] = contrib;
    __syncthreads();
    for (int s2 = 128; s2 > 0; s2 >>= 1) {
        if (t < s2) red[t] += red[t + s2];
        __syncthreads();
    }
    if (t == 0) ws[WS_PRE + h] = red[0];
}

__device__ __forceinline__ void load_quad(const float* __restrict__ codes,
                                          long long q, int lane, f32x4 v[8])
{
    const f32x4* R = (const f32x4*)codes + ((size_t)q << 9);
#pragma unroll
    for (int r = 0; r < 4; ++r) {
        v[2 * r]     = __builtin_nontemporal_load(R + r * 128 + lane);
        v[2 * r + 1] = __builtin_nontemporal_load(R + r * 128 + 64 + lane);
    }
}

__device__ __forceinline__ void online_merge(float& m, float& s, float m2, float s2)
{
    float mm = fmaxf(m, m2);
    s = s * __expf(m - mm) + s2 * __expf(m2 - mm);
    m = mm;
}

// reduce 4 rows x 4 heads; lane ends with e for (head=lane&3, row=(lane>>2)&3)
__device__ __forceinline__ void compute_quad(
    const f32x4 v[8], const f32x4 w2a[H], const f32x4 w2b[H],
    float mypre, int lane, int hsel, bool b0, bool b1, bool b2, bool b3,
    long long q, int n_codes, float* __restrict__ e_out, float& m, float& s)
{
    float A[4][H];
#pragma unroll
    for (int r = 0; r < 4; ++r)
#pragma unroll
        for (int h = 0; h < H; ++h) {
            A[r][h] = v[2*r].x * w2a[h].x + v[2*r].y * w2a[h].y +
                      v[2*r].z * w2a[h].z + v[2*r].w * w2a[h].w +
                      v[2*r+1].x * w2b[h].x + v[2*r+1].y * w2b[h].y +
                      v[2*r+1].z * w2b[h].z + v[2*r+1].w * w2b[h].w;
        }
#pragma unroll
    for (int r = 0; r < 4; ++r)
#pragma unroll
        for (int h = 0; h < H; ++h) {
            A[r][h] += __shfl_xor(A[r][h], 1, 64);
            A[r][h] += __shfl_xor(A[r][h], 2, 64);
        }
    float B[4];
#pragma unroll
    for (int r = 0; r < 4; ++r) {
        float t01 = b0 ? A[r][1] : A[r][0];
        float t23 = b0 ? A[r][3] : A[r][2];
        B[r] = b1 ? t23 : t01;
        B[r] += __shfl_xor(B[r], 4, 64);
    }
    float C0 = b2 ? B[1] : B[0];
    float C1 = b2 ? B[3] : B[2];
    C0 += __shfl_xor(C0, 8, 64);
    C1 += __shfl_xor(C1, 8, 64);
    float z = b3 ? C1 : C0;
    z += __shfl_xor(z, 16, 64);
    z += __shfl_xor(z, 32, 64);

    float e = mypre + z;
    e = e >= 0.f ? e : 0.2f * e;
    float mm = fmaxf(m, e);
    s = s * __expf(m - mm) + __expf(e - mm);
    m = mm;
    if (!(lane & 48)) {
        int rowslot = (lane >> 2) & 3;
        e_out[(size_t)hsel * n_codes + ((size_t)q << 2) + rowslot] = e;
    }
}

// Pass B: wave processes 4 rows/iter with register ping-pong prefetch.
__global__ void __launch_bounds__(256) score_kernel(
    const float* __restrict__ codes, const float* __restrict__ ws_in,
    float* __restrict__ e_out, float* __restrict__ ws_out, int n_codes)
{
    const int lane = threadIdx.x & 63;
    const int wid  = threadIdx.x >> 6;
    const int gw   = blockIdx.x * 4 + wid;
    const long long Wtot = (long long)gridDim.x * 4;

    f32x4 w2a[H], w2b[H];
#pragma unroll
    for (int h = 0; h < H; ++h) {
        w2a[h] = *(const f32x4*)&ws_in[WS_W2 + h * CDIM + 4 * lane];
        w2b[h] = *(const f32x4*)&ws_in[WS_W2 + h * CDIM + 256 + 4 * lane];
    }
    const int  hsel = lane & 3;
    const bool b0 = lane & 1, b1 = lane & 2, b2 = lane & 4, b3 = lane & 8;
    const float mypre = ws_in[WS_PRE + hsel];

    const long long nquads = (long long)n_codes >> 2;
    const long long qs = (long long)gw * nquads / Wtot;
    const long long qe = ((long long)gw + 1) * nquads / Wtot;

    float m = -1e30f, s = 0.f;

    f32x4 P[8], Q[8];
    long long q = qs;
    if (q < qe) load_quad(codes, q, lane, P);
    while (q + 2 <= qe) {
        load_quad(codes, q + 1, lane, Q);
        compute_quad(P, w2a, w2b, mypre, lane, hsel, b0, b1, b2, b3,
                     q, n_codes, e_out, m, s);
        if (q + 2 < qe) load_quad(codes, q + 2, lane, P);
        compute_quad(Q, w2a, w2b, mypre, lane, hsel, b0, b1, b2, b3,
                     q + 1, n_codes, e_out, m, s);
        q += 2;
    }
    if (q < qe)
        compute_quad(P, w2a, w2b, mypre, lane, hsel, b0, b1, b2, b3,
                     q, n_codes, e_out, m, s);

    // row tail (n_codes % 4), handled by last wave; zero for n=200000
    if (gw == Wtot - 1) {
        for (int n0 = (int)(nquads << 2); n0 < n_codes; ++n0) {
            const f32x4* R = (const f32x4*)codes + (size_t)n0 * 128;
            f32x4 xa = __builtin_nontemporal_load(R + lane);
            f32x4 xb = __builtin_nontemporal_load(R + 64 + lane);
            float A[H];
#pragma unroll
            for (int h = 0; h < H; ++h) {
                A[h] = xa.x * w2a[h].x + xa.y * w2a[h].y +
                       xa.z * w2a[h].z + xa.w * w2a[h].w +
                       xb.x * w2b[h].x + xb.y * w2b[h].y +
                       xb.z * w2b[h].z + xb.w * w2b[h].w;
                A[h] += __shfl_xor(A[h], 1, 64);
                A[h] += __shfl_xor(A[h], 2, 64);
            }
            float t01 = b0 ? A[1] : A[0], t23 = b0 ? A[3] : A[2];
            float v = b1 ? t23 : t01;
#pragma unroll
            for (int msk = 4; msk <= 32; msk <<= 1) v += __shfl_xor(v, msk, 64);
            float e = mypre + v;
            e = e >= 0.f ? e : 0.2f * e;
            if (!(lane & 12)) {   // exactly one rowslot group absorbs it
                float mm = fmaxf(m, e);
                s = s * __expf(m - mm) + __expf(e - mm);
                m = mm;
            }
            if (lane < H) e_out[(size_t)hsel * n_codes + n0] = e;
        }
    }

    // merge rowslot replicas (bits 2,3); bits 4,5 are identical copies
    {
        float M2 = __shfl_xor(m, 4, 64), S2 = __shfl_xor(s, 4, 64);
        online_merge(m, s, M2, S2);
        M2 = __shfl_xor(m, 8, 64); S2 = __shfl_xor(s, 8, 64);
        online_merge(m, s, M2, S2);
    }

    __shared__ float lm[4][H], ls[4][H];
    if (lane < H) { lm[wid][lane] = m; ls[wid][lane] = s; }
    __syncthreads();
    if (threadIdx.x < H) {
        int h = threadIdx.x;
        float M = -1e30f, S = 0.f;
#pragma unroll
        for (int w = 0; w < 4; ++w) online_merge(M, S, lm[w][h], ls[w][h]);
        float2 v = make_float2(M, S);
        *(float2*)&ws_out[WS_BMS + (size_t)(h * NB + blockIdx.x) * 2] = v;
    }
}

// Pass C: per-block redundant reduce of this head's NB partials, then normalize.
__global__ void __launch_bounds__(256) norm_kernel(
    float* __restrict__ e, const float* __restrict__ ws, int n_codes)
{
    const int h    = blockIdx.y;
    const int lane = threadIdx.x & 63;
    const int wid  = threadIdx.x >> 6;

    float M = -1e30f, S = 0.f;
    const float* Pp = &ws[WS_BMS + (size_t)h * NB * 2];
    for (int i = threadIdx.x; i < NB; i += 256) {
        float2 v = *(const float2*)&Pp[2 * i];
        online_merge(M, S, v.x, v.y);
    }
#pragma unroll
    for (int msk = 1; msk < 64; msk <<= 1) {
        float M2 = __shfl_xor(M, msk, 64), S2 = __shfl_xor(S, msk, 64);
        online_merge(M, S, M2, S2);
    }
    __shared__ float sm[4], ss[4];
    if (lane == 0) { sm[wid] = M; ss[wid] = S; }
    __syncthreads();
    float gm = -1e30f, gs = 0.f;
#pragma unroll
    for (int w = 0; w < 4; ++w) online_merge(gm, gs, sm[w], ss[w]);
    float gi = 1.f / gs;

    int perh4 = n_codes >> 2;
    int idx = blockIdx.x * 256 + threadIdx.x;
    if (idx < perh4) {
        float4* ep = (float4*)(e + (size_t)h * n_codes) + idx;
        float4 v = *ep;
        v.x = __expf(v.x - gm) * gi;
        v.y = __expf(v.y - gm) * gi;
        v.z = __expf(v.z - gm) * gi;
        v.w = __expf(v.w - gm) * gi;
        *ep = v;
    }
    // scalar tail (n_codes % 4) — empty for n=200000
    if (blockIdx.x == 0 && threadIdx.x < (n_codes & 3)) {
        int n0 = (perh4 << 2) + threadIdx.x;
        float x = e[(size_t)h * n_codes + n0];
        e[(size_t)h * n_codes + n0] = __expf(x - gm) * gi;
    }
}

extern "C" void kernel_launch(void* const* d_in, const int* in_sizes, int n_in,
                              void* d_out, int out_size, void* d_ws, size_t ws_size,
                              hipStream_t stream)
{
    const float* pe    = (const float*)d_in[0];   // (1,512)
    const float* codes = (const float*)d_in[1];   // (n,512)
    const float* Ws    = (const float*)d_in[2];   // (4,256,512)
    const float* bs    = (const float*)d_in[3];   // (4,256)
    const float* as_   = (const float*)d_in[4];   // (4,512)
    float* out = (float*)d_out;                   // (4,n)
    float* ws  = (float*)d_ws;
    int n_codes = in_sizes[1] / CDIM;

    prep_kernel<<<H * NCH, 256, 0, stream>>>(pe, Ws, bs, as_, ws);
    score_kernel<<<NB, 256, 0, stream>>>(codes, ws, out, ws, n_codes);
    int perh4 = n_codes >> 2;
    dim3 ngrid((perh4 + 255) / 256, H);
    norm_kernel<<<ngrid, 256, 0, stream>>>(out, ws, n_codes);
}

// Round 7
// 87.897 us; speedup vs baseline: 1.0971x; 1.0971x over previous
//
#include <hip/hip_runtime.h>
#include <hip/hip_bf16.h>

#define H     4
#define HID   256
#define CDIM  512
#define NCH   32              // d-chunks in prepA
#define DPER  (HID / NCH)     // 8 rows per chunk
#define NB    1024            // blocks in score pass (4/CU, single round)

typedef float f32x4 __attribute__((ext_vector_type(4)));

// ws layout (float offsets)
#define WS_P1   0                        // H*NCH*CDIM  w1 partials
#define WS_P2   (WS_P1 + H * NCH * CDIM) // H*NCH*CDIM  w2 partials
#define WS_W2   (WS_P2 + H * NCH * CDIM) // H*CDIM
#define WS_PRE  (WS_W2 + H * CDIM)       // H
#define WS_BMS  (WS_PRE + H)             // H*NB*2 (max,sum interleaved)

// Pass A1: partial w1/w2 over d-chunks. 128 blocks, each reads 16KB contiguous.
__global__ void __launch_bounds__(256) prepA_kernel(
    const float* __restrict__ Ws, const float* __restrict__ as_,
    float* __restrict__ ws)
{
    int h = blockIdx.x >> 5, chunk = blockIdx.x & (NCH - 1);
    int t = threadIdx.x;
    const float* W  = Ws + ((size_t)h * HID + chunk * DPER) * CDIM;
    const float* a1 = as_ + (size_t)h * 2 * HID + chunk * DPER;
    const float* a2 = a1 + HID;
    int c0 = t, c1 = t + 256;
    float w1a = 0.f, w1b = 0.f, w2a = 0.f, w2b = 0.f;
#pragma unroll
    for (int d = 0; d < DPER; ++d) {
        float x0 = W[d * CDIM + c0], x1 = W[d * CDIM + c1];
        float v1 = a1[d], v2 = a2[d];
        w1a = fmaf(v1, x0, w1a); w2a = fmaf(v2, x0, w2a);
        w1b = fmaf(v1, x1, w1b); w2b = fmaf(v2, x1, w2b);
    }
    size_t base = (size_t)(h * NCH + chunk) * CDIM;
    ws[WS_P1 + base + c0] = w1a; ws[WS_P1 + base + c1] = w1b;
    ws[WS_P2 + base + c0] = w2a; ws[WS_P2 + base + c1] = w2b;
}

// Pass A2: reduce chunk partials -> w2[h,c]; pre[h] = pe.w1 + bs.(a1+a2)
__global__ void __launch_bounds__(256) prepB_kernel(
    const float* __restrict__ pe, const float* __restrict__ bs,
    const float* __restrict__ as_, float* __restrict__ ws)
{
    int h = blockIdx.x;
    int t = threadIdx.x;
    int c0 = t, c1 = t + 256;
    float w1a = 0.f, w1b = 0.f, w2a = 0.f, w2b = 0.f;
#pragma unroll
    for (int k = 0; k < NCH; ++k) {
        size_t base = (size_t)(h * NCH + k) * CDIM;
        w1a += ws[WS_P1 + base + c0]; w1b += ws[WS_P1 + base + c1];
        w2a += ws[WS_P2 + base + c0]; w2b += ws[WS_P2 + base + c1];
    }
    ws[WS_W2 + h * CDIM + c0] = w2a;
    ws[WS_W2 + h * CDIM + c1] = w2b;
    const float* a1 = as_ + (size_t)h * 2 * HID;
    const float* a2 = a1 + HID;
    float contrib = w1a * pe[c0] + w1b * pe[c1];
    contrib += bs[h * HID + t] * (a1[t] + a2[t]);
    __shared__ float red[256];
    red[t] = contrib;
    __syncthreads();
    for (int s2 = 128; s2 > 0; s2 >>= 1) {
        if (t < s2) red[t] += red[t + s2];
        __syncthreads();
    }
    if (t == 0) ws[WS_PRE + h] = red[0];
}

__device__ __forceinline__ void load_quad(const float* __restrict__ codes,
                                          long long q, int lane, f32x4 v[8])
{
    const f32x4* R = (const f32x4*)codes + ((size_t)q << 9);
#pragma unroll
    for (int r = 0; r < 4; ++r) {
        v[2 * r]     = __builtin_nontemporal_load(R + r * 128 + lane);
        v[2 * r + 1] = __builtin_nontemporal_load(R + r * 128 + 64 + lane);
    }
}

__device__ __forceinline__ void online_merge(float& m, float& s, float m2, float s2)
{
    float mm = fmaxf(m, m2);
    s = s * __expf(m - mm) + s2 * __expf(m2 - mm);
    m = mm;
}

// Select-early transpose reduction: 32 DS ops per quad (was 40).
// merge bit0 -> keep h0==b0; merge bit1 -> keep h1==b1; merge bit2 ->
// keep r0==b2; merge bit3 -> keep r1==b3; merge bits 4,5 plain.
// Lane ends with e for (head=lane&3, row=(lane>>2)&3), 4x replicated.
__device__ __forceinline__ void compute_quad(
    const f32x4 v[8], const f32x4 w2a[H], const f32x4 w2b[H],
    float mypre, int lane, int hsel, bool b0, bool b1, bool b2, bool b3,
    long long q, int n_codes, float* __restrict__ e_out, float& m, float& s)
{
    float A[4][H];
#pragma unroll
    for (int r = 0; r < 4; ++r)
#pragma unroll
        for (int h = 0; h < H; ++h) {
            A[r][h] = v[2*r].x * w2a[h].x + v[2*r].y * w2a[h].y +
                      v[2*r].z * w2a[h].z + v[2*r].w * w2a[h].w +
                      v[2*r+1].x * w2b[h].x + v[2*r+1].y * w2b[h].y +
                      v[2*r+1].z * w2b[h].z + v[2*r+1].w * w2b[h].w;
        }
    // stage 1: 16 DS, then keep h0 == b0  (8 values)
#pragma unroll
    for (int r = 0; r < 4; ++r)
#pragma unroll
        for (int h = 0; h < H; ++h)
            A[r][h] += __shfl_xor(A[r][h], 1, 64);
    float B[4][2];
#pragma unroll
    for (int r = 0; r < 4; ++r) {
        B[r][0] = b0 ? A[r][1] : A[r][0];
        B[r][1] = b0 ? A[r][3] : A[r][2];
    }
    // stage 2: 8 DS, keep h1 == b1  (4 values)
#pragma unroll
    for (int r = 0; r < 4; ++r) {
        B[r][0] += __shfl_xor(B[r][0], 2, 64);
        B[r][1] += __shfl_xor(B[r][1], 2, 64);
    }
    float C[4];
#pragma unroll
    for (int r = 0; r < 4; ++r) C[r] = b1 ? B[r][1] : B[r][0];
    // stage 3: 4 DS, keep r0 == b2  (2 values)
#pragma unroll
    for (int r = 0; r < 4; ++r) C[r] += __shfl_xor(C[r], 4, 64);
    float D0 = b2 ? C[1] : C[0];
    float D1 = b2 ? C[3] : C[2];
    // stage 4: 2 DS, keep r1 == b3  (1 value)
    D0 += __shfl_xor(D0, 8, 64);
    D1 += __shfl_xor(D1, 8, 64);
    float z = b3 ? D1 : D0;
    // stages 5,6: plain
    z += __shfl_xor(z, 16, 64);
    z += __shfl_xor(z, 32, 64);

    float e = mypre + z;
    e = e >= 0.f ? e : 0.2f * e;
    float mm = fmaxf(m, e);
    s = s * __expf(m - mm) + __expf(e - mm);
    m = mm;
    if (!(lane & 48)) {
        int rowslot = (lane >> 2) & 3;
        e_out[(size_t)hsel * n_codes + ((size_t)q << 2) + rowslot] = e;
    }
}

// Pass B: wave processes 4 rows/iter with register ping-pong prefetch.
__global__ void __launch_bounds__(256, 4) score_kernel(
    const float* __restrict__ codes, const float* __restrict__ ws_in,
    float* __restrict__ e_out, float* __restrict__ ws_out, int n_codes)
{
    const int lane = threadIdx.x & 63;
    const int wid  = threadIdx.x >> 6;
    const int gw   = blockIdx.x * 4 + wid;
    const long long Wtot = (long long)gridDim.x * 4;

    f32x4 w2a[H], w2b[H];
#pragma unroll
    for (int h = 0; h < H; ++h) {
        w2a[h] = *(const f32x4*)&ws_in[WS_W2 + h * CDIM + 4 * lane];
        w2b[h] = *(const f32x4*)&ws_in[WS_W2 + h * CDIM + 256 + 4 * lane];
    }
    const int  hsel = lane & 3;
    const bool b0 = lane & 1, b1 = lane & 2, b2 = lane & 4, b3 = lane & 8;
    const float mypre = ws_in[WS_PRE + hsel];

    const long long nquads = (long long)n_codes >> 2;
    const long long qs = (long long)gw * nquads / Wtot;
    const long long qe = ((long long)gw + 1) * nquads / Wtot;

    float m = -1e30f, s = 0.f;

    f32x4 P[8], Q[8];
    long long q = qs;
    if (q < qe) load_quad(codes, q, lane, P);
    while (q + 2 <= qe) {
        load_quad(codes, q + 1, lane, Q);
        compute_quad(P, w2a, w2b, mypre, lane, hsel, b0, b1, b2, b3,
                     q, n_codes, e_out, m, s);
        if (q + 2 < qe) load_quad(codes, q + 2, lane, P);
        compute_quad(Q, w2a, w2b, mypre, lane, hsel, b0, b1, b2, b3,
                     q + 1, n_codes, e_out, m, s);
        q += 2;
    }
    if (q < qe)
        compute_quad(P, w2a, w2b, mypre, lane, hsel, b0, b1, b2, b3,
                     q, n_codes, e_out, m, s);

    // row tail (n_codes % 4), handled by last wave; zero for n=200000
    if (gw == Wtot - 1) {
        for (int n0 = (int)(nquads << 2); n0 < n_codes; ++n0) {
            const f32x4* R = (const f32x4*)codes + (size_t)n0 * 128;
            f32x4 xa = __builtin_nontemporal_load(R + lane);
            f32x4 xb = __builtin_nontemporal_load(R + 64 + lane);
            float A[H];
#pragma unroll
            for (int h = 0; h < H; ++h) {
                A[h] = xa.x * w2a[h].x + xa.y * w2a[h].y +
                       xa.z * w2a[h].z + xa.w * w2a[h].w +
                       xb.x * w2b[h].x + xb.y * w2b[h].y +
                       xb.z * w2b[h].z + xb.w * w2b[h].w;
                A[h] += __shfl_xor(A[h], 1, 64);
                A[h] += __shfl_xor(A[h], 2, 64);
            }
            float t01 = b0 ? A[1] : A[0], t23 = b0 ? A[3] : A[2];
            float v = b1 ? t23 : t01;
#pragma unroll
            for (int msk = 4; msk <= 32; msk <<= 1) v += __shfl_xor(v, msk, 64);
            float e = mypre + v;
            e = e >= 0.f ? e : 0.2f * e;
            if (!(lane & 12)) {   // exactly one rowslot group absorbs it
                float mm = fmaxf(m, e);
                s = s * __expf(m - mm) + __expf(e - mm);
                m = mm;
            }
            if (lane < H) e_out[(size_t)hsel * n_codes + n0] = e;
        }
    }

    // merge rowslot replicas (bits 2,3); bits 4,5 are identical copies
    {
        float M2 = __shfl_xor(m, 4, 64), S2 = __shfl_xor(s, 4, 64);
        online_merge(m, s, M2, S2);
        M2 = __shfl_xor(m, 8, 64); S2 = __shfl_xor(s, 8, 64);
        online_merge(m, s, M2, S2);
    }

    __shared__ float lm[4][H], ls[4][H];
    if (lane < H) { lm[wid][lane] = m; ls[wid][lane] = s; }
    __syncthreads();
    if (threadIdx.x < H) {
        int h = threadIdx.x;
        float M = -1e30f, S = 0.f;
#pragma unroll
        for (int w = 0; w < 4; ++w) online_merge(M, S, lm[w][h], ls[w][h]);
        float2 v = make_float2(M, S);
        *(float2*)&ws_out[WS_BMS + (size_t)(h * NB + blockIdx.x) * 2] = v;
    }
}

// Pass C: per-block redundant reduce of this head's NB partials, then normalize.
__global__ void __launch_bounds__(256) norm_kernel(
    float* __restrict__ e, const float* __restrict__ ws, int n_codes)
{
    const int h    = blockIdx.y;
    const int lane = threadIdx.x & 63;
    const int wid  = threadIdx.x >> 6;

    float M = -1e30f, S = 0.f;
    const float* Pp = &ws[WS_BMS + (size_t)h * NB * 2];
    for (int i = threadIdx.x; i < NB; i += 256) {
        float2 v = *(const float2*)&Pp[2 * i];
        online_merge(M, S, v.x, v.y);
    }
#pragma unroll
    for (int msk = 1; msk < 64; msk <<= 1) {
        float M2 = __shfl_xor(M, msk, 64), S2 = __shfl_xor(S, msk, 64);
        online_merge(M, S, M2, S2);
    }
    __shared__ float sm[4], ss[4];
    if (lane == 0) { sm[wid] = M; ss[wid] = S; }
    __syncthreads();
    float gm = -1e30f, gs = 0.f;
#pragma unroll
    for (int w = 0; w < 4; ++w) online_merge(gm, gs, sm[w], ss[w]);
    float gi = 1.f / gs;

    int perh4 = n_codes >> 2;
    int idx = blockIdx.x * 256 + threadIdx.x;
    if (idx < perh4) {
        float4* ep = (float4*)(e + (size_t)h * n_codes) + idx;
        float4 v = *ep;
        v.x = __expf(v.x - gm) * gi;
        v.y = __expf(v.y - gm) * gi;
        v.z = __expf(v.z - gm) * gi;
        v.w = __expf(v.w - gm) * gi;
        *ep = v;
    }
    // scalar tail (n_codes % 4) — empty for n=200000
    if (blockIdx.x == 0 && threadIdx.x < (n_codes & 3)) {
        int n0 = (perh4 << 2) + threadIdx.x;
        float x = e[(size_t)h * n_codes + n0];
        e[(size_t)h * n_codes + n0] = __expf(x - gm) * gi;
    }
}

extern "C" void kernel_launch(void* const* d_in, const int* in_sizes, int n_in,
                              void* d_out, int out_size, void* d_ws, size_t ws_size,
                              hipStream_t stream)
{
    const float* pe    = (const float*)d_in[0];   // (1,512)
    const float* codes = (const float*)d_in[1];   // (n,512)
    const float* Ws    = (const float*)d_in[2];   // (4,256,512)
    const float* bs    = (const float*)d_in[3];   // (4,256)
    const float* as_   = (const float*)d_in[4];   // (4,512)
    float* out = (float*)d_out;                   // (4,n)
    float* ws  = (float*)d_ws;
    int n_codes = in_sizes[1] / CDIM;

    prepA_kernel<<<H * NCH, 256, 0, stream>>>(Ws, as_, ws);
    prepB_kernel<<<H, 256, 0, stream>>>(pe, bs, as_, ws);
    score_kernel<<<NB, 256, 0, stream>>>(codes, ws, out, ws, n_codes);
    int perh4 = n_codes >> 2;
    dim3 ngrid((perh4 + 255) / 256, H);
    norm_kernel<<<ngrid, 256, 0, stream>>>(out, ws, n_codes);
}

// Round 8
// 85.071 us; speedup vs baseline: 1.1336x; 1.0332x over previous
//
#include <hip/hip_runtime.h>
#include <hip/hip_bf16.h>

#define H     4
#define HID   256
#define CDIM  512
#define NCH   32              // d-chunks in prepA
#define DPER  (HID / NCH)     // 8 rows per chunk
#define NB    1024            // blocks in score pass (4/CU, single round)

typedef float f32x4 __attribute__((ext_vector_type(4)));

// ws layout (float offsets)
#define WS_P1   0                        // H*NCH*CDIM  w1 partials
#define WS_P2   (WS_P1 + H * NCH * CDIM) // H*NCH*CDIM  w2 partials
#define WS_W2   (WS_P2 + H * NCH * CDIM) // H*CDIM
#define WS_PRE  (WS_W2 + H * CDIM)       // H
#define WS_BMS  (WS_PRE + H)             // H*NB*2 (max,sum interleaved)

// Pass A1: partial w1/w2 over d-chunks. 128 blocks, each reads 16KB contiguous.
__global__ void __launch_bounds__(256) prepA_kernel(
    const float* __restrict__ Ws, const float* __restrict__ as_,
    float* __restrict__ ws)
{
    int h = blockIdx.x >> 5, chunk = blockIdx.x & (NCH - 1);
    int t = threadIdx.x;
    const float* W  = Ws + ((size_t)h * HID + chunk * DPER) * CDIM;
    const float* a1 = as_ + (size_t)h * 2 * HID + chunk * DPER;
    const float* a2 = a1 + HID;
    int c0 = t, c1 = t + 256;
    float w1a = 0.f, w1b = 0.f, w2a = 0.f, w2b = 0.f;
#pragma unroll
    for (int d = 0; d < DPER; ++d) {
        float x0 = W[d * CDIM + c0], x1 = W[d * CDIM + c1];
        float v1 = a1[d], v2 = a2[d];
        w1a = fmaf(v1, x0, w1a); w2a = fmaf(v2, x0, w2a);
        w1b = fmaf(v1, x1, w1b); w2b = fmaf(v2, x1, w2b);
    }
    size_t base = (size_t)(h * NCH + chunk) * CDIM;
    ws[WS_P1 + base + c0] = w1a; ws[WS_P1 + base + c1] = w1b;
    ws[WS_P2 + base + c0] = w2a; ws[WS_P2 + base + c1] = w2b;
}

// Pass A2: reduce chunk partials -> w2[h,c]; pre[h] = pe.w1 + bs.(a1+a2)
__global__ void __launch_bounds__(256) prepB_kernel(
    const float* __restrict__ pe, const float* __restrict__ bs,
    const float* __restrict__ as_, float* __restrict__ ws)
{
    int h = blockIdx.x;
    int t = threadIdx.x;
    int c0 = t, c1 = t + 256;
    float w1a = 0.f, w1b = 0.f, w2a = 0.f, w2b = 0.f;
#pragma unroll
    for (int k = 0; k < NCH; ++k) {
        size_t base = (size_t)(h * NCH + k) * CDIM;
        w1a += ws[WS_P1 + base + c0]; w1b += ws[WS_P1 + base + c1];
        w2a += ws[WS_P2 + base + c0]; w2b += ws[WS_P2 + base + c1];
    }
    ws[WS_W2 + h * CDIM + c0] = w2a;
    ws[WS_W2 + h * CDIM + c1] = w2b;
    const float* a1 = as_ + (size_t)h * 2 * HID;
    const float* a2 = a1 + HID;
    float contrib = w1a * pe[c0] + w1b * pe[c1];
    contrib += bs[h * HID + t] * (a1[t] + a2[t]);
    __shared__ float red[256];
    red[t] = contrib;
    __syncthreads();
    for (int s2 = 128; s2 > 0; s2 >>= 1) {
        if (t < s2) red[t] += red[t + s2];
        __syncthreads();
    }
    if (t == 0) ws[WS_PRE + h] = red[0];
}

__device__ __forceinline__ void load_quad(const float* __restrict__ codes,
                                          long long q, int lane, f32x4 v[8])
{
    const f32x4* R = (const f32x4*)codes + ((size_t)q << 9);
#pragma unroll
    for (int r = 0; r < 4; ++r) {
        v[2 * r]     = __builtin_nontemporal_load(R + r * 128 + lane);
        v[2 * r + 1] = __builtin_nontemporal_load(R + r * 128 + 64 + lane);
    }
}

__device__ __forceinline__ void online_merge(float& m, float& s, float m2, float s2)
{
    float mm = fmaxf(m, m2);
    s = s * __expf(m - mm) + s2 * __expf(m2 - mm);
    m = mm;
}

// Select-early transpose reduction: 32 DS ops per quad.
// Lane ends with e for (head=lane&3, row=(lane>>2)&3), 4x replicated.
__device__ __forceinline__ void compute_quad(
    const f32x4 v[8], const f32x4 w2a[H], const f32x4 w2b[H],
    float mypre, int lane, int hsel, bool b0, bool b1, bool b2, bool b3,
    long long q, int n_codes, float* __restrict__ e_out, float& m, float& s)
{
    float A[4][H];
#pragma unroll
    for (int r = 0; r < 4; ++r)
#pragma unroll
        for (int h = 0; h < H; ++h) {
            A[r][h] = v[2*r].x * w2a[h].x + v[2*r].y * w2a[h].y +
                      v[2*r].z * w2a[h].z + v[2*r].w * w2a[h].w +
                      v[2*r+1].x * w2b[h].x + v[2*r+1].y * w2b[h].y +
                      v[2*r+1].z * w2b[h].z + v[2*r+1].w * w2b[h].w;
        }
#pragma unroll
    for (int r = 0; r < 4; ++r)
#pragma unroll
        for (int h = 0; h < H; ++h)
            A[r][h] += __shfl_xor(A[r][h], 1, 64);
    float B[4][2];
#pragma unroll
    for (int r = 0; r < 4; ++r) {
        B[r][0] = b0 ? A[r][1] : A[r][0];
        B[r][1] = b0 ? A[r][3] : A[r][2];
    }
#pragma unroll
    for (int r = 0; r < 4; ++r) {
        B[r][0] += __shfl_xor(B[r][0], 2, 64);
        B[r][1] += __shfl_xor(B[r][1], 2, 64);
    }
    float C[4];
#pragma unroll
    for (int r = 0; r < 4; ++r) C[r] = b1 ? B[r][1] : B[r][0];
#pragma unroll
    for (int r = 0; r < 4; ++r) C[r] += __shfl_xor(C[r], 4, 64);
    float D0 = b2 ? C[1] : C[0];
    float D1 = b2 ? C[3] : C[2];
    D0 += __shfl_xor(D0, 8, 64);
    D1 += __shfl_xor(D1, 8, 64);
    float z = b3 ? D1 : D0;
    z += __shfl_xor(z, 16, 64);
    z += __shfl_xor(z, 32, 64);

    float e = mypre + z;
    e = e >= 0.f ? e : 0.2f * e;
    float mm = fmaxf(m, e);
    s = s * __expf(m - mm) + __expf(e - mm);
    m = mm;
    if (!(lane & 48)) {
        int rowslot = (lane >> 2) & 3;
        e_out[(size_t)hsel * n_codes + ((size_t)q << 2) + rowslot] = e;
    }
}

// Pass B: block-cooperative streaming. Each block owns a contiguous quad
// range; its 4 waves interleave by quad (stride 4) so the block marches
// ~sequentially through one ~390KB region (fewer DRAM streams).
__global__ void __launch_bounds__(256, 4) score_kernel(
    const float* __restrict__ codes, const float* __restrict__ ws_in,
    float* __restrict__ e_out, float* __restrict__ ws_out, int n_codes)
{
    const int lane = threadIdx.x & 63;
    const int wid  = threadIdx.x >> 6;

    f32x4 w2a[H], w2b[H];
#pragma unroll
    for (int h = 0; h < H; ++h) {
        w2a[h] = *(const f32x4*)&ws_in[WS_W2 + h * CDIM + 4 * lane];
        w2b[h] = *(const f32x4*)&ws_in[WS_W2 + h * CDIM + 256 + 4 * lane];
    }
    const int  hsel = lane & 3;
    const bool b0 = lane & 1, b1 = lane & 2, b2 = lane & 4, b3 = lane & 8;
    const float mypre = ws_in[WS_PRE + hsel];

    const long long nquads = (long long)n_codes >> 2;
    const long long qs0 = (long long)blockIdx.x * nquads / gridDim.x;
    const long long qe0 = ((long long)blockIdx.x + 1) * nquads / gridDim.x;

    float m = -1e30f, s = 0.f;

    f32x4 P[8], Q[8];
    long long q = qs0 + wid;
    const long long cnt = (qe0 > q) ? ((qe0 - q + 3) >> 2) : 0;
    if (cnt > 0) load_quad(codes, q, lane, P);
    long long i = 0;
    for (; i + 2 <= cnt; i += 2) {
        load_quad(codes, q + 4, lane, Q);
        compute_quad(P, w2a, w2b, mypre, lane, hsel, b0, b1, b2, b3,
                     q, n_codes, e_out, m, s);
        if (i + 2 < cnt) load_quad(codes, q + 8, lane, P);
        compute_quad(Q, w2a, w2b, mypre, lane, hsel, b0, b1, b2, b3,
                     q + 4, n_codes, e_out, m, s);
        q += 8;
    }
    if (i < cnt)
        compute_quad(P, w2a, w2b, mypre, lane, hsel, b0, b1, b2, b3,
                     q, n_codes, e_out, m, s);

    // row tail (n_codes % 4), handled by last block; zero for n=200000
    if (blockIdx.x == gridDim.x - 1 && wid == 3) {
        for (int n0 = (int)(nquads << 2); n0 < n_codes; ++n0) {
            const f32x4* R = (const f32x4*)codes + (size_t)n0 * 128;
            f32x4 xa = __builtin_nontemporal_load(R + lane);
            f32x4 xb = __builtin_nontemporal_load(R + 64 + lane);
            float A[H];
#pragma unroll
            for (int h = 0; h < H; ++h) {
                A[h] = xa.x * w2a[h].x + xa.y * w2a[h].y +
                       xa.z * w2a[h].z + xa.w * w2a[h].w +
                       xb.x * w2b[h].x + xb.y * w2b[h].y +
                       xb.z * w2b[h].z + xb.w * w2b[h].w;
                A[h] += __shfl_xor(A[h], 1, 64);
                A[h] += __shfl_xor(A[h], 2, 64);
            }
            float t01 = b0 ? A[1] : A[0], t23 = b0 ? A[3] : A[2];
            float v = b1 ? t23 : t01;
#pragma unroll
            for (int msk = 4; msk <= 32; msk <<= 1) v += __shfl_xor(v, msk, 64);
            float e = mypre + v;
            e = e >= 0.f ? e : 0.2f * e;
            if (!(lane & 12)) {
                float mm = fmaxf(m, e);
                s = s * __expf(m - mm) + __expf(e - mm);
                m = mm;
            }
            if (lane < H) e_out[(size_t)hsel * n_codes + n0] = e;
        }
    }

    // merge rowslot replicas (bits 2,3); bits 4,5 are identical copies
    {
        float M2 = __shfl_xor(m, 4, 64), S2 = __shfl_xor(s, 4, 64);
        online_merge(m, s, M2, S2);
        M2 = __shfl_xor(m, 8, 64); S2 = __shfl_xor(s, 8, 64);
        online_merge(m, s, M2, S2);
    }

    __shared__ float lm[4][H], ls[4][H];
    if (lane < H) { lm[wid][lane] = m; ls[wid][lane] = s; }
    __syncthreads();
    if (threadIdx.x < H) {
        int h = threadIdx.x;
        float M = -1e30f, S = 0.f;
#pragma unroll
        for (int w = 0; w < 4; ++w) online_merge(M, S, lm[w][h], ls[w][h]);
        float2 v = make_float2(M, S);
        *(float2*)&ws_out[WS_BMS + (size_t)(h * NB + blockIdx.x) * 2] = v;
    }
}

// Pass C: per-block redundant reduce of this head's NB partials, then normalize.
__global__ void __launch_bounds__(256) norm_kernel(
    float* __restrict__ e, const float* __restrict__ ws, int n_codes)
{
    const int h    = blockIdx.y;
    const int lane = threadIdx.x & 63;
    const int wid  = threadIdx.x >> 6;

    float M = -1e30f, S = 0.f;
    const float* Pp = &ws[WS_BMS + (size_t)h * NB * 2];
    for (int i = threadIdx.x; i < NB; i += 256) {
        float2 v = *(const float2*)&Pp[2 * i];
        online_merge(M, S, v.x, v.y);
    }
#pragma unroll
    for (int msk = 1; msk < 64; msk <<= 1) {
        float M2 = __shfl_xor(M, msk, 64), S2 = __shfl_xor(S, msk, 64);
        online_merge(M, S, M2, S2);
    }
    __shared__ float sm[4], ss[4];
    if (lane == 0) { sm[wid] = M; ss[wid] = S; }
    __syncthreads();
    float gm = -1e30f, gs = 0.f;
#pragma unroll
    for (int w = 0; w < 4; ++w) online_merge(gm, gs, sm[w], ss[w]);
    float gi = 1.f / gs;

    int perh4 = n_codes >> 2;
    int idx = blockIdx.x * 256 + threadIdx.x;
    if (idx < perh4) {
        float4* ep = (float4*)(e + (size_t)h * n_codes) + idx;
        float4 v = *ep;
        v.x = __expf(v.x - gm) * gi;
        v.y = __expf(v.y - gm) * gi;
        v.z = __expf(v.z - gm) * gi;
        v.w = __expf(v.w - gm) * gi;
        *ep = v;
    }
    // scalar tail (n_codes % 4) — empty for n=200000
    if (blockIdx.x == 0 && threadIdx.x < (n_codes & 3)) {
        int n0 = (perh4 << 2) + threadIdx.x;
        float x = e[(size_t)h * n_codes + n0];
        e[(size_t)h * n_codes + n0] = __expf(x - gm) * gi;
    }
}

extern "C" void kernel_launch(void* const* d_in, const int* in_sizes, int n_in,
                              void* d_out, int out_size, void* d_ws, size_t ws_size,
                              hipStream_t stream)
{
    const float* pe    = (const float*)d_in[0];   // (1,512)
    const float* codes = (const float*)d_in[1];   // (n,512)
    const float* Ws    = (const float*)d_in[2];   // (4,256,512)
    const float* bs    = (const float*)d_in[3];   // (4,256)
    const float* as_   = (const float*)d_in[4];   // (4,512)
    float* out = (float*)d_out;                   // (4,n)
    float* ws  = (float*)d_ws;
    int n_codes = in_sizes[1] / CDIM;

    prepA_kernel<<<H * NCH, 256, 0, stream>>>(Ws, as_, ws);
    prepB_kernel<<<H, 256, 0, stream>>>(pe, bs, as_, ws);
    score_kernel<<<NB, 256, 0, stream>>>(codes, ws, out, ws, n_codes);
    int perh4 = n_codes >> 2;
    dim3 ngrid((perh4 + 255) / 256, H);
    norm_kernel<<<ngrid, 256, 0, stream>>>(out, ws, n_codes);
}